// Round 21
// baseline (63.023 us; speedup 1.0000x reference)
//
#include <hip/hip_runtime.h>

#define NB 128
#define NTOK 201
#define EW 210   // u-slot holding the att-col-0 (e-column) weight

// Publish LDS writes across a barrier WITHOUT draining vmcnt.
__device__ __forceinline__ void lds_barrier() {
    asm volatile("s_waitcnt lgkmcnt(0)" ::: "memory");
    __builtin_amdgcn_s_barrier();
}

// u^T <- u^T * att_e[l], l = 10..0, u0 = row 0 of att_e[11].
// r17 structure (one barrier/layer, per-wave private reduce) with the k-loop
// restructured into BATCHES OF 8: eight global_load_dwordx4 issued
// back-to-back (8 quads in flight per wave instead of the compiler's ~4),
// then eight weight-FMA groups consume them. All batch registers die within
// the phase -> no cross-barrier liveness -> no scratch-spill mode.
template<int M>
__device__ __forceinline__ void chain4(
    const float* __restrict__ xb, float* __restrict__ out,
    const int e, const int b, const int lo,
    float (*u4)[212], float (*part)[4][212], float* rv, int* rix)
{
    constexpr int W4   = (M + 5) / 4;     // active float4 col-groups (50 / 26)
    constexpr int NK   = (M + 3) / 4;     // rows per thread (50 / 25)
    constexpr int NREG = NK - 1;          // regular rows (49 / 24)
    constexpr int NBAT = NREG / 8;        // full batches (6 / 3)

    const int tid = threadIdx.x;
    const int g   = tid & 63;
    const int w   = tid >> 6;            // wave index 0..3

    const size_t plane = (size_t)NTOK * NTOK;
    const float* L11 = xb + (size_t)(11 * NB) * plane + (size_t)e * NTOK;

    const int trg = (b + 2 * lo - 1 + w) & 3;
    const int C   = lo - trg;            // 16B-aligned start col for this wave
    const int sel = (b + lo - 1 + w + e) & 3;   // col e's comp in lane-W4 quads
    const int col0 = (g < W4) ? (C + 4 * g) : (e - sel);

    float* uw = u4[w];                   // this wave's private u copy

    // init: each wave fills its own copy (slots outside [3,M+2) stay 0 forever)
    #pragma unroll
    for (int k2 = 0; k2 < 4; ++k2) {
        const int s = g + 64 * k2;
        if (s < 212) {
            float v = 0.f;
            if (s >= 3 && s < M + 2) v = L11[lo - 3 + s];
            if (s == EW)             v = L11[e];
            uw[s] = v;
        }
    }
    __syncthreads();

    const size_t rstep = (size_t)(4 * NTOK);
    const float* A = xb + (size_t)(10 * NB) * plane;
    int pb = 0;

    for (int l = 10; l >= 0; --l) {
        if (g <= W4) {
            float4 acc = make_float4(0.f, 0.f, 0.f, 0.f);
            float shead = 0.f;
            if (w == 0) {                // att row 0 = x row e (wave 0 only)
                const float hw = uw[EW];
                if (g < W4) {
                    const float* hp = A + (size_t)e * NTOK + col0;
                    acc.x = hw * hp[0]; acc.y = hw * hp[1];
                    acc.z = hw * hp[2]; acc.w = hw * hp[3];
                } else {                 // scalar head: avoids OOB quad at e=0
                    shead = hw * A[(size_t)e * NTOK + e];
                }
            }
            const float* rp = A + (size_t)(lo - 1 + w) * NTOK + col0;
            // batched rows: 8 loads issued back-to-back, then 8 FMA groups
            #pragma unroll 1
            for (int kb = 0; kb < NBAT; ++kb) {
                const float* rpb = rp + rstep * (8 * kb);
                float4 ab[8];
                #pragma unroll
                for (int i = 0; i < 8; ++i)
                    ab[i] = *(const float4*)(rpb + rstep * i);
                #pragma unroll
                for (int i = 0; i < 8; ++i) {
                    const float wt = uw[w + 2 + 4 * (8 * kb + i)];
                    acc.x += wt * ab[i].x; acc.y += wt * ab[i].y;
                    acc.z += wt * ab[i].z; acc.w += wt * ab[i].w;
                }
            }
            // remainder rows (heavy: k=48), then the clamped tail row
            #pragma unroll
            for (int k = 8 * NBAT; k < NREG; ++k) {
                const float wt = uw[w + 2 + 4 * k];
                const float4 a = *(const float4*)(rp + rstep * k);
                acc.x += wt * a.x; acc.y += wt * a.y;
                acc.z += wt * a.z; acc.w += wt * a.w;
            }
            {   // tail row, in-class clamp for r >= M (zero weight there)
                constexpr int k = NK - 1;
                const int r = w + 4 * k;
                const float wt = uw[r + 2];
                const float4 a = *(const float4*)(rp + rstep * k
                                                  - ((r >= M) ? rstep : 0));
                acc.x += wt * a.x; acc.y += wt * a.y;
                acc.z += wt * a.z; acc.w += wt * a.w;
            }
            if (g < W4) {
                *(float4*)&part[pb][w][4 * g] = acc;
            } else {
                const float se = (sel == 0) ? acc.x :
                                 (sel == 1) ? acc.y :
                                 (sel == 2) ? acc.z : acc.w;
                part[pb][w][EW] = se + shead;
            }
        }
        lds_barrier();                   // the ONLY barrier per layer
        // per-wave FULL reduce: part[pb] -> uw (all 64 lanes, 4 slots each)
        #pragma unroll
        for (int k2 = 0; k2 < 4; ++k2) {
            const int p = 3 + g + 64 * k2;
            if (p < M + 2) {
                float s = 0.f;
                #pragma unroll
                for (int q = 0; q < 4; ++q) {
                    const int tq = (b + 2 * lo - 1 + q) & 3;
                    s += part[pb][q][p - 3 + tq];   // undo per-wave col shift
                }
                uw[p] = s;
            } else if (p == EW) {
                uw[EW] = part[pb][0][EW] + part[pb][1][EW]
                       + part[pb][2][EW] + part[pb][3][EW];
            }
        }
        pb ^= 1;                         // next FMA writes the other buffer
        A -= (size_t)NB * plane;
    }

    // max + argmax over p in [3, M+2); each thread reads its OWN wave's copy
    {
        float v = -INFINITY; int idx = 0x7fffffff;
        if (tid >= 3 && tid < M + 2) { v = uw[tid]; idx = tid; }
        rv[tid] = v; rix[tid] = idx;
    }
    __syncthreads();
    for (int s = 128; s > 0; s >>= 1) {
        if (tid < s) {
            const float v2 = rv[tid + s]; const int i2 = rix[tid + s];
            if (v2 > rv[tid] || (v2 == rv[tid] && i2 < rix[tid])) {
                rv[tid] = v2; rix[tid] = i2;
            }
        }
        __syncthreads();
    }
    if (tid == 0) {
        out[e * NB + b]       = rv[0];
        out[640 + e * NB + b] = (float)(lo - 3 + rix[0]);   // = (j-1) + lo
    }
}

// bid = 128*e + b => bid%8 = b%8: all 5 chains of a batch on the SAME XCD
// (shared L2 dedups overlapping plane reads). 640 small blocks -> ~2.5
// independent chains/CU whose phases interleave (MLP across blocks).
__global__ __launch_bounds__(256, 4) void part_att_kernel(
    const float* __restrict__ x, float* __restrict__ out)
{
    __shared__ float u4[4][212];         // per-wave private u copies
    __shared__ float part[2][4][212];    // double-buffered partials
    __shared__ float rv[256];
    __shared__ int   rix[256];

    const int bid = blockIdx.x;
    const int e   = bid >> 7;
    const int b   = bid & 127;
    const float* xb = x + (size_t)b * ((size_t)NTOK * NTOK);

    if (e < 2) {
        chain4<197>(xb, out, e, b, 5, u4, part, rv, rix);
    } else {
        const int lo = (e == 2) ? 5 : (e == 3) ? 54 : 103;
        chain4<99>(xb, out, e, b, lo, u4, part, rv, rix);
    }
}

extern "C" void kernel_launch(void* const* d_in, const int* in_sizes, int n_in,
                              void* d_out, int out_size, void* d_ws, size_t ws_size,
                              hipStream_t stream) {
    (void)in_sizes; (void)n_in; (void)d_ws; (void)ws_size; (void)out_size;
    const float* x = (const float*)d_in[0];
    float* out = (float*)d_out;
    part_att_kernel<<<dim3(640), dim3(256), 0, stream>>>(x, out);
}

// Round 22
// 45.665 us; speedup vs baseline: 1.3801x; 1.3801x over previous
//
#include <hip/hip_runtime.h>

#define NB 128
#define NTOK 201
#define EW 210   // u-slot holding the att-col-0 (e-column) weight

// Publish LDS writes across a barrier WITHOUT draining vmcnt.
__device__ __forceinline__ void lds_barrier() {
    asm volatile("s_waitcnt lgkmcnt(0)" ::: "memory");
    __builtin_amdgcn_s_barrier();
}

// u^T <- u^T * att_e[l], l = 10..0, u0 = row 0 of att_e[11].
// 256 threads = 64 col-groups (g) x 4 waves (w: rows r === w mod 4).
// Padded-col space p = xcol-(lo-3), valid [3,M+2), e-weight at u[EW].
// Per-wave 16B-aligned start col C_w; per-wave col shift undone in the reduce.
// Rows r >= M clamp in-class (r-4), auto-masked by zero weight u[r+2].
// e-column folded into the float4 loop (lane g==W4, quad base e-sel).
// ONE barrier per layer: each wave redundantly computes the FULL reduce into
// its PRIVATE u copy u4[w], and part is double-buffered (a wave reusing
// buffer A at FMA(l-2) has passed bar(l-1), which guarantees all waves'
// reduce(l) reads of A are done).
template<int M>
__device__ __forceinline__ void chain4(
    const float* __restrict__ xb, float* __restrict__ out,
    const int e, const int b, const int lo,
    float (*u4)[212], float (*part)[4][212], float* rv, int* rix)
{
    constexpr int W4 = (M + 5) / 4;      // active float4 col-groups (50 / 26)
    constexpr int NK = (M + 3) / 4;      // rows per thread (50 / 25)

    const int tid = threadIdx.x;
    const int g   = tid & 63;
    const int w   = tid >> 6;            // wave index 0..3

    const size_t plane = (size_t)NTOK * NTOK;
    const float* L11 = xb + (size_t)(11 * NB) * plane + (size_t)e * NTOK;

    const int trg = (b + 2 * lo - 1 + w) & 3;
    const int C   = lo - trg;            // 16B-aligned start col for this wave
    const int sel = (b + lo - 1 + w + e) & 3;   // col e's comp in lane-W4 quads
    const int col0 = (g < W4) ? (C + 4 * g) : (e - sel);

    float* uw = u4[w];                   // this wave's private u copy

    // init: each wave fills its own copy (slots outside [3,M+2) stay 0 forever)
    #pragma unroll
    for (int k2 = 0; k2 < 4; ++k2) {
        const int s = g + 64 * k2;
        if (s < 212) {
            float v = 0.f;
            if (s >= 3 && s < M + 2) v = L11[lo - 3 + s];
            if (s == EW)             v = L11[e];
            uw[s] = v;
        }
    }
    __syncthreads();

    const size_t rstep = (size_t)(4 * NTOK);
    const float* A = xb + (size_t)(10 * NB) * plane;
    int pb = 0;

    for (int l = 10; l >= 0; --l) {
        if (g <= W4) {
            float4 acc = make_float4(0.f, 0.f, 0.f, 0.f);
            float shead = 0.f;
            if (w == 0) {                // att row 0 = x row e (wave 0 only)
                const float hw = uw[EW];
                if (g < W4) {
                    const float* hp = A + (size_t)e * NTOK + col0;
                    acc.x = hw * hp[0]; acc.y = hw * hp[1];
                    acc.z = hw * hp[2]; acc.w = hw * hp[3];
                } else {                 // scalar head: avoids OOB quad at e=0
                    shead = hw * A[(size_t)e * NTOK + e];
                }
            }
            const float* rp = A + (size_t)(lo - 1 + w) * NTOK + col0;
            #pragma unroll
            for (int k = 0; k < NK - 1; ++k) {
                const float wt = uw[w + 2 + 4 * k];
                const float4 a = *(const float4*)(rp + rstep * k);
                acc.x += wt * a.x; acc.y += wt * a.y;
                acc.z += wt * a.z; acc.w += wt * a.w;
            }
            {   // tail row, in-class clamp for r >= M (zero weight there)
                constexpr int k = NK - 1;
                const int r = w + 4 * k;
                const float wt = uw[r + 2];
                const float4 a = *(const float4*)(rp + rstep * k
                                                  - ((r >= M) ? rstep : 0));
                acc.x += wt * a.x; acc.y += wt * a.y;
                acc.z += wt * a.z; acc.w += wt * a.w;
            }
            if (g < W4) {
                *(float4*)&part[pb][w][4 * g] = acc;
            } else {
                const float se = (sel == 0) ? acc.x :
                                 (sel == 1) ? acc.y :
                                 (sel == 2) ? acc.z : acc.w;
                part[pb][w][EW] = se + shead;
            }
        }
        lds_barrier();                   // the ONLY barrier per layer
        // per-wave FULL reduce: part[pb] -> uw (all 64 lanes, 4 slots each)
        #pragma unroll
        for (int k2 = 0; k2 < 4; ++k2) {
            const int p = 3 + g + 64 * k2;
            if (p < M + 2) {
                float s = 0.f;
                #pragma unroll
                for (int q = 0; q < 4; ++q) {
                    const int tq = (b + 2 * lo - 1 + q) & 3;
                    s += part[pb][q][p - 3 + tq];   // undo per-wave col shift
                }
                uw[p] = s;
            } else if (p == EW) {
                uw[EW] = part[pb][0][EW] + part[pb][1][EW]
                       + part[pb][2][EW] + part[pb][3][EW];
            }
        }
        pb ^= 1;                         // next FMA writes the other buffer
        A -= (size_t)NB * plane;
    }

    // max + argmax over p in [3, M+2); each thread reads its OWN wave's copy
    {
        float v = -INFINITY; int idx = 0x7fffffff;
        if (tid >= 3 && tid < M + 2) { v = uw[tid]; idx = tid; }
        rv[tid] = v; rix[tid] = idx;
    }
    __syncthreads();
    for (int s = 128; s > 0; s >>= 1) {
        if (tid < s) {
            const float v2 = rv[tid + s]; const int i2 = rix[tid + s];
            if (v2 > rv[tid] || (v2 == rv[tid] && i2 < rix[tid])) {
                rv[tid] = v2; rix[tid] = i2;
            }
        }
        __syncthreads();
    }
    if (tid == 0) {
        out[e * NB + b]       = rv[0];
        out[640 + e * NB + b] = (float)(lo - 3 + rix[0]);   // = (j-1) + lo
    }
}

// bid = 128*e + b => bid%8 = b%8: all 5 chains of a batch on the SAME XCD
// (shared L2 dedups overlapping plane reads). 640 small blocks -> ~2.5
// independent chains/CU whose phases interleave (MLP across blocks).
__global__ __launch_bounds__(256, 4) void part_att_kernel(
    const float* __restrict__ x, float* __restrict__ out)
{
    __shared__ float u4[4][212];         // per-wave private u copies
    __shared__ float part[2][4][212];    // double-buffered partials
    __shared__ float rv[256];
    __shared__ int   rix[256];

    const int bid = blockIdx.x;
    const int e   = bid >> 7;
    const int b   = bid & 127;
    const float* xb = x + (size_t)b * ((size_t)NTOK * NTOK);

    if (e < 2) {
        chain4<197>(xb, out, e, b, 5, u4, part, rv, rix);
    } else {
        const int lo = (e == 2) ? 5 : (e == 3) ? 54 : 103;
        chain4<99>(xb, out, e, b, lo, u4, part, rv, rix);
    }
}

extern "C" void kernel_launch(void* const* d_in, const int* in_sizes, int n_in,
                              void* d_out, int out_size, void* d_ws, size_t ws_size,
                              hipStream_t stream) {
    (void)in_sizes; (void)n_in; (void)d_ws; (void)ws_size; (void)out_size;
    const float* x = (const float*)d_in[0];
    float* out = (float*)d_out;
    part_att_kernel<<<dim3(640), dim3(256), 0, stream>>>(x, out);
}